// Round 1
// baseline (322.667 us; speedup 1.0000x reference)
//
#include <hip/hip_runtime.h>
#include <hip/hip_bf16.h>

#define NTOK 2048
#define CDIM 1024
#define NH 8
#define HD 128

typedef short bf16x8 __attribute__((ext_vector_type(8)));
typedef float f32x4 __attribute__((ext_vector_type(4)));
typedef unsigned short u16x4 __attribute__((ext_vector_type(4)));
typedef unsigned short u16x8 __attribute__((ext_vector_type(8)));

static __device__ __forceinline__ unsigned short f2b(float f) {
  __hip_bfloat16 h = __float2bfloat16(f);
  return *reinterpret_cast<unsigned short*>(&h);
}

// K0a: x_cls f32 -> bf16 (row-major [2048][1024])
__global__ __launch_bounds__(256) void k_cvt_x(const float* __restrict__ x,
                                               unsigned short* __restrict__ xb) {
  int i = (blockIdx.x * 256 + threadIdx.x) * 4;
  float4 v = *reinterpret_cast<const float4*>(x + i);
  u16x4 o; o[0] = f2b(v.x); o[1] = f2b(v.y); o[2] = f2b(v.z); o[3] = f2b(v.w);
  *reinterpret_cast<u16x4*>(xb + i) = o;
}

// K0b: WvT[j][k] = bf16(W[k][2048+j]) — transposed V-slice of W_cls
__global__ __launch_bounds__(256) void k_wt(const float* __restrict__ W,
                                            unsigned short* __restrict__ wt) {
  int idx = blockIdx.x * 256 + threadIdx.x;   // 1M threads
  int j = idx >> 10, k = idx & 1023;
  wt[idx] = f2b(W[k * 3072 + 2048 + j]);
}

// K1: v = x @ Wv  (M=2048, N=1024, K=1024), bf16 MFMA 16x16x32, 64x64 tile, 4 waves.
// Writes v into out0[:, 1024+j] (this IS the x_ori output, and serves as v storage).
__global__ __launch_bounds__(256) void k_gemm_v(const unsigned short* __restrict__ xb,
                                                const unsigned short* __restrict__ wt,
                                                float* __restrict__ out0) {
  int j0 = blockIdx.x * 64, n0 = blockIdx.y * 64;
  int t = threadIdx.x, w = t >> 6, l = t & 63, g = l >> 4, c = l & 15;
  const unsigned short* arow = xb + (n0 + w * 16 + c) * CDIM + g * 8;
  f32x4 acc[4] = {};
  for (int kk = 0; kk < CDIM; kk += 32) {
    bf16x8 a = *reinterpret_cast<const bf16x8*>(arow + kk);
#pragma unroll
    for (int cf = 0; cf < 4; ++cf) {
      bf16x8 b = *reinterpret_cast<const bf16x8*>(wt + (j0 + cf * 16 + c) * CDIM + kk + g * 8);
      acc[cf] = __builtin_amdgcn_mfma_f32_16x16x32_bf16(a, b, acc[cf], 0, 0, 0);
    }
  }
#pragma unroll
  for (int cf = 0; cf < 4; ++cf)
#pragma unroll
    for (int r = 0; r < 4; ++r)
      out0[(n0 + w * 16 + g * 4 + r) * (2 * CDIM) + CDIM + j0 + cf * 16 + c] = acc[cf][r];
}

// K2: per (h, n): inv-norm over 128 dims; write vn bf16 [h][n][d] (normalized)
// and vT bf16 [h][d][n] (unnormalized, for PV B-operand).
__global__ __launch_bounds__(256) void k_norm(const float* __restrict__ out0,
                                              unsigned short* __restrict__ vn,
                                              unsigned short* __restrict__ vT) {
  int h = blockIdx.x, n0 = blockIdx.y * 64;
  int t = threadIdx.x;
  int i = t >> 2, dq = (t & 3) * 32;
  __shared__ float red[64][4];
  __shared__ float invn[64];
  __shared__ unsigned short tile[64][136];  // padded: avoid bank conflicts on transpose read
  float v[32];
  const float* src = out0 + (n0 + i) * 2048 + 1024 + h * 128 + dq;
  float ss = 0.f;
#pragma unroll
  for (int x = 0; x < 32; x += 4) {
    float4 f = *reinterpret_cast<const float4*>(src + x);
    v[x] = f.x; v[x + 1] = f.y; v[x + 2] = f.z; v[x + 3] = f.w;
    ss += f.x * f.x + f.y * f.y + f.z * f.z + f.w * f.w;
  }
  red[i][t & 3] = ss;
#pragma unroll
  for (int x = 0; x < 32; ++x) tile[i][dq + x] = f2b(v[x]);
  __syncthreads();
  if ((t & 3) == 0) invn[i] = rsqrtf(red[i][0] + red[i][1] + red[i][2] + red[i][3]);
  __syncthreads();
  float inv = invn[i];
  unsigned short* dn = vn + (h * NTOK + n0 + i) * HD + dq;
#pragma unroll
  for (int x = 0; x < 32; x += 8) {
    u16x8 o;
#pragma unroll
    for (int q = 0; q < 8; ++q) o[q] = f2b(v[x + q] * inv);
    *reinterpret_cast<u16x8*>(dn + x) = o;
  }
  int q = t & 3;
#pragma unroll
  for (int pass = 0; pass < 2; ++pass) {
    int dd = (t >> 2) + pass * 64;
    u16x8 a, b;
#pragma unroll
    for (int nn = 0; nn < 8; ++nn) a[nn] = tile[q * 16 + nn][dd];
#pragma unroll
    for (int nn = 0; nn < 8; ++nn) b[nn] = tile[q * 16 + 8 + nn][dd];
    unsigned short* dT = vT + (h * HD + dd) * NTOK + n0 + q * 16;
    *reinterpret_cast<u16x8*>(dT) = a;
    *reinterpret_cast<u16x8*>(dT + 8) = b;
  }
}

// K3: per (h, 64-row tile): full m loop: S = vn@vn^T (K=128); e = exp(25(S-1));
// denom = rowsum(e); X += e@v. Writes X/denom into out0[:, h*128..] and denom to ws.
__global__ __launch_bounds__(256) void k_attn_x(const unsigned short* __restrict__ vn,
                                                const unsigned short* __restrict__ vT,
                                                float* __restrict__ out0,
                                                float* __restrict__ denom_ws) {
  int h = blockIdx.x, n0 = blockIdx.y * 64;
  int t = threadIdx.x, w = t >> 6, l = t & 63, g = l >> 4, c = l & 15;
  __shared__ unsigned short elds[4][16][80];  // per-wave e tile, 16B-aligned rows
  const unsigned short* vnh = vn + h * NTOK * HD;
  const unsigned short* vTh = vT + h * HD * NTOK;
  const unsigned short* arow = vnh + (n0 + w * 16 + c) * HD + g * 8;
  bf16x8 afr[4];
#pragma unroll
  for (int ks = 0; ks < 4; ++ks) afr[ks] = *reinterpret_cast<const bf16x8*>(arow + ks * 32);
  f32x4 xacc[8] = {};
  float rs[4] = {0.f, 0.f, 0.f, 0.f};
  for (int m0 = 0; m0 < NTOK; m0 += 64) {
    f32x4 sacc[4] = {};
#pragma unroll
    for (int ks = 0; ks < 4; ++ks) {
#pragma unroll
      for (int cf = 0; cf < 4; ++cf) {
        bf16x8 b = *reinterpret_cast<const bf16x8*>(vnh + (m0 + cf * 16 + c) * HD + ks * 32 + g * 8);
        sacc[cf] = __builtin_amdgcn_mfma_f32_16x16x32_bf16(afr[ks], b, sacc[cf], 0, 0, 0);
      }
    }
#pragma unroll
    for (int cf = 0; cf < 4; ++cf)
#pragma unroll
      for (int r = 0; r < 4; ++r) {
        float e = __expf(25.0f * (sacc[cf][r] - 1.0f));
        rs[r] += e;
        elds[w][g * 4 + r][cf * 16 + c] = f2b(e);
      }
    // PV: X += P @ V  (A-frag re-read from LDS in MFMA-A layout)
#pragma unroll
    for (int ks2 = 0; ks2 < 2; ++ks2) {
      bf16x8 pa = *reinterpret_cast<const bf16x8*>(&elds[w][c][ks2 * 32 + g * 8]);
#pragma unroll
      for (int dc = 0; dc < 8; ++dc) {
        bf16x8 bv = *reinterpret_cast<const bf16x8*>(vTh + (dc * 16 + c) * NTOK + m0 + ks2 * 32 + g * 8);
        xacc[dc] = __builtin_amdgcn_mfma_f32_16x16x32_bf16(pa, bv, xacc[dc], 0, 0, 0);
      }
    }
  }
  // full rowsum within each 16-lane group (rows = g*4+r)
#pragma unroll
  for (int r = 0; r < 4; ++r) {
    float vsum = rs[r];
    vsum += __shfl_xor(vsum, 1);
    vsum += __shfl_xor(vsum, 2);
    vsum += __shfl_xor(vsum, 4);
    vsum += __shfl_xor(vsum, 8);
    rs[r] = vsum;
  }
  if (c == 0) {
#pragma unroll
    for (int r = 0; r < 4; ++r) denom_ws[h * NTOK + n0 + w * 16 + g * 4 + r] = rs[r];
  }
#pragma unroll
  for (int dc = 0; dc < 8; ++dc)
#pragma unroll
    for (int r = 0; r < 4; ++r)
      out0[(n0 + w * 16 + g * 4 + r) * 2048 + h * HD + dc * 16 + c] = xacc[dc][r] / rs[r];
}

// K4: per (m-split, 64-row tile): recompute S for all 8 heads, accumulate
// raw-sum (mask) and sim = sum_h e_h/denom_h; write unnormalized out1; atomic row sums.
__global__ __launch_bounds__(256) void k_sim(const unsigned short* __restrict__ vn,
                                             const float* __restrict__ denom_ws,
                                             float* __restrict__ out1,
                                             float* __restrict__ rowsum) {
  int s = blockIdx.x, n0 = blockIdx.y * 64;
  int t = threadIdx.x, w = t >> 6, l = t & 63, g = l >> 4, c = l & 15;
  float invd[NH][4];
#pragma unroll
  for (int h = 0; h < NH; ++h)
#pragma unroll
    for (int r = 0; r < 4; ++r)
      invd[h][r] = 1.0f / denom_ws[h * NTOK + n0 + w * 16 + g * 4 + r];
  float rowacc[4] = {0.f, 0.f, 0.f, 0.f};
  for (int mt = 0; mt < 4; ++mt) {
    int m0 = s * 256 + mt * 64;
    float raw[4][4] = {};
    float sim[4][4] = {};
#pragma unroll
    for (int h = 0; h < NH; ++h) {
      const unsigned short* vnh = vn + h * NTOK * HD;
      f32x4 sacc[4] = {};
#pragma unroll
      for (int ks = 0; ks < 4; ++ks) {
        bf16x8 a = *reinterpret_cast<const bf16x8*>(vnh + (n0 + w * 16 + c) * HD + ks * 32 + g * 8);
#pragma unroll
        for (int cf = 0; cf < 4; ++cf) {
          bf16x8 b = *reinterpret_cast<const bf16x8*>(vnh + (m0 + cf * 16 + c) * HD + ks * 32 + g * 8);
          sacc[cf] = __builtin_amdgcn_mfma_f32_16x16x32_bf16(a, b, sacc[cf], 0, 0, 0);
        }
      }
#pragma unroll
      for (int cf = 0; cf < 4; ++cf)
#pragma unroll
        for (int r = 0; r < 4; ++r) {
          float sv = sacc[cf][r];
          raw[cf][r] += sv;
          sim[cf][r] += __expf(25.0f * (sv - 1.0f)) * invd[h][r];
        }
    }
#pragma unroll
    for (int cf = 0; cf < 4; ++cf)
#pragma unroll
      for (int r = 0; r < 4; ++r) {
        // mask: mean_h raw > 0.75  <=>  sum_h raw > 6.0 ; softmax denoms cancel.
        float val = (raw[cf][r] > 6.0f) ? __expf(sim[cf][r] * 0.125f) : 0.0f;
        out1[(n0 + w * 16 + g * 4 + r) * NTOK + m0 + cf * 16 + c] = val;
        rowacc[r] += val;
      }
  }
#pragma unroll
  for (int r = 0; r < 4; ++r) {
    float vsum = rowacc[r];
    vsum += __shfl_xor(vsum, 1);
    vsum += __shfl_xor(vsum, 2);
    vsum += __shfl_xor(vsum, 4);
    vsum += __shfl_xor(vsum, 8);
    rowacc[r] = vsum;
  }
  if (c == 0) {
#pragma unroll
    for (int r = 0; r < 4; ++r)
      atomicAdd(&rowsum[n0 + w * 16 + g * 4 + r], rowacc[r]);
  }
}

// K5: normalize out1 rows by masked-exp row sums.
__global__ __launch_bounds__(256) void k_renorm(float* __restrict__ out1,
                                                const float* __restrict__ rowsum) {
  int row = blockIdx.x;
  float inv = 1.0f / rowsum[row];
  float4* p = reinterpret_cast<float4*>(out1 + row * NTOK);
  for (int c4 = threadIdx.x; c4 < NTOK / 4; c4 += 256) {
    float4 v = p[c4];
    v.x *= inv; v.y *= inv; v.z *= inv; v.w *= inv;
    p[c4] = v;
  }
}

extern "C" void kernel_launch(void* const* d_in, const int* in_sizes, int n_in,
                              void* d_out, int out_size, void* d_ws, size_t ws_size,
                              hipStream_t stream) {
  const float* x_cls = (const float*)d_in[0];
  const float* W_cls = (const float*)d_in[2];
  // d_in[1] (x_reg) and d_in[3] (W_reg) do not feed the outputs.
  float* out0 = (float*)d_out;                 // [2048][2048] = concat(x, x_ori)
  float* out1 = out0 + NTOK * 2 * CDIM / 1;    // actually NTOK*2048
  out1 = (float*)d_out + (size_t)NTOK * 2048;  // [2048][2048] sim_round2

  unsigned short* xb = (unsigned short*)d_ws;               // 2M shorts (4MB)
  unsigned short* wt = xb + NTOK * CDIM;                    // 1M shorts (2MB)
  unsigned short* vn = wt + CDIM * CDIM;                    // 2M shorts (4MB)
  unsigned short* vT = vn + NH * NTOK * HD;                 // 2M shorts (4MB)
  float* denom = (float*)(vT + NH * HD * NTOK);             // 16K floats
  float* rowsum = denom + NH * NTOK;                        // 2048 floats

  hipMemsetAsync(rowsum, 0, NTOK * sizeof(float), stream);
  k_cvt_x<<<2048, 256, 0, stream>>>(x_cls, xb);
  k_wt<<<4096, 256, 0, stream>>>(W_cls, wt);
  k_gemm_v<<<dim3(16, 32), 256, 0, stream>>>(xb, wt, out0);
  k_norm<<<dim3(8, 32), 256, 0, stream>>>(out0, vn, vT);
  k_attn_x<<<dim3(8, 32), 256, 0, stream>>>(vn, vT, out0, denom);
  k_sim<<<dim3(8, 32), 256, 0, stream>>>(vn, denom, out1, rowsum);
  k_renorm<<<NTOK, 256, 0, stream>>>(out1, rowsum);
}

// Round 2
// 214.331 us; speedup vs baseline: 1.5055x; 1.5055x over previous
//
#include <hip/hip_runtime.h>
#include <hip/hip_bf16.h>

#define NTOK 2048
#define CDIM 1024
#define NH 8
#define HD 128

typedef short bf16x8 __attribute__((ext_vector_type(8)));
typedef float f32x4 __attribute__((ext_vector_type(4)));
typedef unsigned short u16x4 __attribute__((ext_vector_type(4)));
typedef unsigned short u16x8 __attribute__((ext_vector_type(8)));

static __device__ __forceinline__ unsigned short f2b(float f) {
  __hip_bfloat16 h = __float2bfloat16(f);
  return *reinterpret_cast<unsigned short*>(&h);
}

// K0a: x_cls f32 -> bf16 (row-major [2048][1024])
__global__ __launch_bounds__(256) void k_cvt_x(const float* __restrict__ x,
                                               unsigned short* __restrict__ xb) {
  int i = (blockIdx.x * 256 + threadIdx.x) * 4;
  float4 v = *reinterpret_cast<const float4*>(x + i);
  u16x4 o; o[0] = f2b(v.x); o[1] = f2b(v.y); o[2] = f2b(v.z); o[3] = f2b(v.w);
  *reinterpret_cast<u16x4*>(xb + i) = o;
}

// K0b: WvT[j][k] = bf16(W[k][2048+j]) — transposed V-slice of W_cls
__global__ __launch_bounds__(256) void k_wt(const float* __restrict__ W,
                                            unsigned short* __restrict__ wt) {
  int idx = blockIdx.x * 256 + threadIdx.x;   // 1M threads
  int j = idx >> 10, k = idx & 1023;
  wt[idx] = f2b(W[k * 3072 + 2048 + j]);
}

// K1: v = x @ Wv  (M=2048, N=1024, K=1024), bf16 MFMA 16x16x32, 64x64 tile, 4 waves.
// Writes v into out0[:, 1024+j] (this IS the x_ori output, and serves as v storage).
__global__ __launch_bounds__(256) void k_gemm_v(const unsigned short* __restrict__ xb,
                                                const unsigned short* __restrict__ wt,
                                                float* __restrict__ out0) {
  int j0 = blockIdx.x * 64, n0 = blockIdx.y * 64;
  int t = threadIdx.x, w = t >> 6, l = t & 63, g = l >> 4, c = l & 15;
  const unsigned short* arow = xb + (n0 + w * 16 + c) * CDIM + g * 8;
  f32x4 acc[4] = {};
  for (int kk = 0; kk < CDIM; kk += 32) {
    bf16x8 a = *reinterpret_cast<const bf16x8*>(arow + kk);
#pragma unroll
    for (int cf = 0; cf < 4; ++cf) {
      bf16x8 b = *reinterpret_cast<const bf16x8*>(wt + (j0 + cf * 16 + c) * CDIM + kk + g * 8);
      acc[cf] = __builtin_amdgcn_mfma_f32_16x16x32_bf16(a, b, acc[cf], 0, 0, 0);
    }
  }
#pragma unroll
  for (int cf = 0; cf < 4; ++cf)
#pragma unroll
    for (int r = 0; r < 4; ++r)
      out0[(n0 + w * 16 + g * 4 + r) * (2 * CDIM) + CDIM + j0 + cf * 16 + c] = acc[cf][r];
}

// K2: per (h, n): inv-norm over 128 dims; write vn bf16 [h][n][d] (normalized)
// and vT bf16 [h][d][n] (unnormalized, for PV B-operand).
__global__ __launch_bounds__(256) void k_norm(const float* __restrict__ out0,
                                              unsigned short* __restrict__ vn,
                                              unsigned short* __restrict__ vT) {
  int h = blockIdx.x, n0 = blockIdx.y * 64;
  int t = threadIdx.x;
  int i = t >> 2, dq = (t & 3) * 32;
  __shared__ float red[64][4];
  __shared__ float invn[64];
  __shared__ unsigned short tile[64][136];
  float v[32];
  const float* src = out0 + (n0 + i) * 2048 + 1024 + h * 128 + dq;
  float ss = 0.f;
#pragma unroll
  for (int x = 0; x < 32; x += 4) {
    float4 f = *reinterpret_cast<const float4*>(src + x);
    v[x] = f.x; v[x + 1] = f.y; v[x + 2] = f.z; v[x + 3] = f.w;
    ss += f.x * f.x + f.y * f.y + f.z * f.z + f.w * f.w;
  }
  red[i][t & 3] = ss;
#pragma unroll
  for (int x = 0; x < 32; ++x) tile[i][dq + x] = f2b(v[x]);
  __syncthreads();
  if ((t & 3) == 0) invn[i] = rsqrtf(red[i][0] + red[i][1] + red[i][2] + red[i][3]);
  __syncthreads();
  float inv = invn[i];
  unsigned short* dn = vn + (h * NTOK + n0 + i) * HD + dq;
#pragma unroll
  for (int x = 0; x < 32; x += 8) {
    u16x8 o;
#pragma unroll
    for (int q = 0; q < 8; ++q) o[q] = f2b(v[x + q] * inv);
    *reinterpret_cast<u16x8*>(dn + x) = o;
  }
  int q = t & 3;
#pragma unroll
  for (int pass = 0; pass < 2; ++pass) {
    int dd = (t >> 2) + pass * 64;
    u16x8 a, b;
#pragma unroll
    for (int nn = 0; nn < 8; ++nn) a[nn] = tile[q * 16 + nn][dd];
#pragma unroll
    for (int nn = 0; nn < 8; ++nn) b[nn] = tile[q * 16 + 8 + nn][dd];
    unsigned short* dT = vT + (h * HD + dd) * NTOK + n0 + q * 16;
    *reinterpret_cast<u16x8*>(dT) = a;
    *reinterpret_cast<u16x8*>(dT + 8) = b;
  }
}

// K3 v2: grid (8 h, 64 tiles of 32 rows), 512 threads = 8 waves.
// Each wave owns a private m-chunk set (j*8+w)*64, j=0..3: computes S = vn@vn^T,
// e = exp(25(S-1)), partial denom, and partial X += e @ v with a wave-private
// XOR-swizzled P tile in LDS. NO barriers in the main loop (8 independent
// waves/CU). Partials combined at the end via LDS slots.
#define XROW 132
#define XSLOT (32 * XROW)
__global__ __launch_bounds__(512, 2) void k_attn_x(const unsigned short* __restrict__ vn,
                                                   const unsigned short* __restrict__ vT,
                                                   float* __restrict__ out0,
                                                   float* __restrict__ denom_ws) {
  int h = blockIdx.x, n0 = blockIdx.y * 32;
  int t = threadIdx.x, w = t >> 6, l = t & 63, g = l >> 4, c = l & 15;
  // [0,67584): X slots 4 x [32][XROW] f32 ; P (8 waves x 4KB) aliases [0,32768) during loop
  // [67584,68608): denom slots [8][32] f32 ; [68608,68736): inv_denom [32] f32
  __shared__ __align__(16) unsigned char smem[68736];
  const unsigned short* vnh = vn + h * NTOK * HD;
  const unsigned short* vTh = vT + h * HD * NTOK;
  // hoisted A-frags: rows n0..n0+31
  bf16x8 afr[2][4];
#pragma unroll
  for (int rf = 0; rf < 2; ++rf)
#pragma unroll
    for (int ks = 0; ks < 4; ++ks)
      afr[rf][ks] = *reinterpret_cast<const bf16x8*>(vnh + (n0 + rf * 16 + c) * HD + ks * 32 + g * 8);
  f32x4 xacc[2][8] = {};
  float rs[8] = {0.f, 0.f, 0.f, 0.f, 0.f, 0.f, 0.f, 0.f};
#pragma unroll 1
  for (int j = 0; j < 4; ++j) {
    int m0 = (j * 8 + w) * 64;
    f32x4 sacc[2][4] = {};
#pragma unroll
    for (int ks = 0; ks < 4; ++ks) {
      bf16x8 bks[4];
#pragma unroll
      for (int cf = 0; cf < 4; ++cf)
        bks[cf] = *reinterpret_cast<const bf16x8*>(vnh + (m0 + cf * 16 + c) * HD + ks * 32 + g * 8);
#pragma unroll
      for (int rf = 0; rf < 2; ++rf)
#pragma unroll
        for (int cf = 0; cf < 4; ++cf)
          sacc[rf][cf] = __builtin_amdgcn_mfma_f32_16x16x32_bf16(afr[rf][ks], bks[cf], sacc[rf][cf], 0, 0, 0);
    }
    // exp + write wave-private P (swizzled: byte ^= (row&7)<<4 within 128B rows)
#pragma unroll
    for (int rf = 0; rf < 2; ++rf)
#pragma unroll
      for (int cf = 0; cf < 4; ++cf)
#pragma unroll
        for (int r = 0; r < 4; ++r) {
          float e = __expf(25.0f * (sacc[rf][cf][r] - 1.0f));
          rs[rf * 4 + r] += e;
          int row = rf * 16 + g * 4 + r;
          int byte = (row * 128 + (cf * 16 + c) * 2) ^ ((row & 7) << 4);
          *reinterpret_cast<unsigned short*>(smem + w * 4096 + byte) = f2b(e);
        }
    // PV: X += P @ V
#pragma unroll
    for (int ks2 = 0; ks2 < 2; ++ks2) {
      bf16x8 bv[8];
#pragma unroll
      for (int dc = 0; dc < 8; ++dc)
        bv[dc] = *reinterpret_cast<const bf16x8*>(vTh + (dc * 16 + c) * NTOK + m0 + ks2 * 32 + g * 8);
#pragma unroll
      for (int rf = 0; rf < 2; ++rf) {
        int prow = rf * 16 + c;
        int pbyte = (prow * 128 + (ks2 * 32 + g * 8) * 2) ^ ((prow & 7) << 4);
        bf16x8 pa = *reinterpret_cast<const bf16x8*>(smem + w * 4096 + pbyte);
#pragma unroll
        for (int dc = 0; dc < 8; ++dc)
          xacc[rf][dc] = __builtin_amdgcn_mfma_f32_16x16x32_bf16(pa, bv[dc], xacc[rf][dc], 0, 0, 0);
      }
    }
  }
  // denom partial: reduce over the 16 c-lanes
#pragma unroll
  for (int i = 0; i < 8; ++i) {
    float v = rs[i];
    v += __shfl_xor(v, 1); v += __shfl_xor(v, 2);
    v += __shfl_xor(v, 4); v += __shfl_xor(v, 8);
    rs[i] = v;
  }
  __syncthreads();  // P now dead; X slots safe
  float* xs = reinterpret_cast<float*>(smem);
  float* dslot = reinterpret_cast<float*>(smem + 67584);
  float* idn = reinterpret_cast<float*>(smem + 68608);
  if (w < 4) {
#pragma unroll
    for (int rf = 0; rf < 2; ++rf)
#pragma unroll
      for (int dc = 0; dc < 8; ++dc)
#pragma unroll
        for (int r = 0; r < 4; ++r)
          xs[w * XSLOT + (rf * 16 + g * 4 + r) * XROW + dc * 16 + c] = xacc[rf][dc][r];
  }
  if (c == 0) {
#pragma unroll
    for (int rf = 0; rf < 2; ++rf)
#pragma unroll
      for (int r = 0; r < 4; ++r)
        dslot[w * 32 + rf * 16 + g * 4 + r] = rs[rf * 4 + r];
  }
  __syncthreads();
  if (w >= 4) {
#pragma unroll
    for (int rf = 0; rf < 2; ++rf)
#pragma unroll
      for (int dc = 0; dc < 8; ++dc)
#pragma unroll
        for (int r = 0; r < 4; ++r)
          xs[(w - 4) * XSLOT + (rf * 16 + g * 4 + r) * XROW + dc * 16 + c] += xacc[rf][dc][r];
  }
  if (t < 32) {
    float d = 0.f;
#pragma unroll
    for (int w8 = 0; w8 < 8; ++w8) d += dslot[w8 * 32 + t];
    denom_ws[h * NTOK + n0 + t] = d;
    idn[t] = 1.0f / d;
  }
  __syncthreads();
  {
    int row = t >> 4, d0 = (t & 15) * 8;
    f32x4 a0 = {}, a1 = {};
#pragma unroll
    for (int s = 0; s < 4; ++s) {
      a0 += *reinterpret_cast<f32x4*>(&xs[s * XSLOT + row * XROW + d0]);
      a1 += *reinterpret_cast<f32x4*>(&xs[s * XSLOT + row * XROW + d0 + 4]);
    }
    float inv = idn[row];
    float* dst = out0 + (size_t)(n0 + row) * 2048 + h * 128 + d0;
    *reinterpret_cast<f32x4*>(dst) = a0 * inv;
    *reinterpret_cast<f32x4*>(dst + 4) = a1 * inv;
  }
}

// K4 v2: grid (32 m-tiles, 32 n-tiles) = 1024 blocks, 4 waves each. One 64x64
// (n,m) tile per block over all 8 heads; mask + sim; atomic row sums.
__global__ __launch_bounds__(256) void k_sim(const unsigned short* __restrict__ vn,
                                             const float* __restrict__ denom_ws,
                                             float* __restrict__ out1,
                                             float* __restrict__ rowsum) {
  int m0 = blockIdx.x * 64, n0 = blockIdx.y * 64;
  int t = threadIdx.x, w = t >> 6, l = t & 63, g = l >> 4, c = l & 15;
  int nr = n0 + w * 16;
  float raw[4][4] = {};
  float sim[4][4] = {};
#pragma unroll 1
  for (int h = 0; h < NH; ++h) {
    const unsigned short* vnh = vn + h * NTOK * HD;
    f32x4 sacc[4] = {};
#pragma unroll
    for (int ks = 0; ks < 4; ++ks) {
      bf16x8 a = *reinterpret_cast<const bf16x8*>(vnh + (nr + c) * HD + ks * 32 + g * 8);
#pragma unroll
      for (int cf = 0; cf < 4; ++cf) {
        bf16x8 b = *reinterpret_cast<const bf16x8*>(vnh + (m0 + cf * 16 + c) * HD + ks * 32 + g * 8);
        sacc[cf] = __builtin_amdgcn_mfma_f32_16x16x32_bf16(a, b, sacc[cf], 0, 0, 0);
      }
    }
    float id[4];
#pragma unroll
    for (int r = 0; r < 4; ++r) id[r] = 1.0f / denom_ws[h * NTOK + nr + g * 4 + r];
#pragma unroll
    for (int cf = 0; cf < 4; ++cf)
#pragma unroll
      for (int r = 0; r < 4; ++r) {
        float sv = sacc[cf][r];
        raw[cf][r] += sv;
        sim[cf][r] += __expf(25.0f * (sv - 1.0f)) * id[r];
      }
  }
  float rowacc[4] = {0.f, 0.f, 0.f, 0.f};
#pragma unroll
  for (int cf = 0; cf < 4; ++cf)
#pragma unroll
    for (int r = 0; r < 4; ++r) {
      // mask: mean_h raw > 0.75  <=>  sum_h raw > 6.0 ; softmax denoms cancel.
      float val = (raw[cf][r] > 6.0f) ? __expf(sim[cf][r] * 0.125f) : 0.0f;
      out1[(size_t)(nr + g * 4 + r) * NTOK + m0 + cf * 16 + c] = val;
      rowacc[r] += val;
    }
#pragma unroll
  for (int r = 0; r < 4; ++r) {
    float v = rowacc[r];
    v += __shfl_xor(v, 1); v += __shfl_xor(v, 2);
    v += __shfl_xor(v, 4); v += __shfl_xor(v, 8);
    rowacc[r] = v;
  }
  if (c == 0) {
#pragma unroll
    for (int r = 0; r < 4; ++r)
      atomicAdd(&rowsum[nr + g * 4 + r], rowacc[r]);
  }
}

// K5: normalize out1 rows by masked-exp row sums.
__global__ __launch_bounds__(256) void k_renorm(float* __restrict__ out1,
                                                const float* __restrict__ rowsum) {
  int row = blockIdx.x;
  float inv = 1.0f / rowsum[row];
  float4* p = reinterpret_cast<float4*>(out1 + (size_t)row * NTOK);
  for (int c4 = threadIdx.x; c4 < NTOK / 4; c4 += 256) {
    float4 v = p[c4];
    v.x *= inv; v.y *= inv; v.z *= inv; v.w *= inv;
    p[c4] = v;
  }
}

extern "C" void kernel_launch(void* const* d_in, const int* in_sizes, int n_in,
                              void* d_out, int out_size, void* d_ws, size_t ws_size,
                              hipStream_t stream) {
  const float* x_cls = (const float*)d_in[0];
  const float* W_cls = (const float*)d_in[2];
  // d_in[1] (x_reg) and d_in[3] (W_reg) do not feed the outputs.
  float* out0 = (float*)d_out;                       // [2048][2048] concat(x, x_ori)
  float* out1 = (float*)d_out + (size_t)NTOK * 2048; // [2048][2048] sim_round2

  unsigned short* xb = (unsigned short*)d_ws;               // 2M shorts (4MB)
  unsigned short* wt = xb + NTOK * CDIM;                    // 1M shorts (2MB)
  unsigned short* vn = wt + CDIM * CDIM;                    // 2M shorts (4MB)
  unsigned short* vT = vn + NH * NTOK * HD;                 // 2M shorts (4MB)
  float* denom = (float*)(vT + NH * HD * NTOK);             // 16K floats
  float* rowsum = denom + NH * NTOK;                        // 2048 floats

  hipMemsetAsync(rowsum, 0, NTOK * sizeof(float), stream);
  k_cvt_x<<<2048, 256, 0, stream>>>(x_cls, xb);
  k_wt<<<4096, 256, 0, stream>>>(W_cls, wt);
  k_gemm_v<<<dim3(16, 32), 256, 0, stream>>>(xb, wt, out0);
  k_norm<<<dim3(8, 32), 256, 0, stream>>>(out0, vn, vT);
  k_attn_x<<<dim3(8, 64), 512, 0, stream>>>(vn, vT, out0, denom);
  k_sim<<<dim3(32, 32), 256, 0, stream>>>(vn, denom, out1, rowsum);
  k_renorm<<<NTOK, 256, 0, stream>>>(out1, rowsum);
}

// Round 4
// 164.161 us; speedup vs baseline: 1.9655x; 1.3056x over previous
//
#include <hip/hip_runtime.h>
#include <hip/hip_bf16.h>

#define NTOK 2048
#define CDIM 1024
#define NH 8
#define HD 128

typedef short bf16x8 __attribute__((ext_vector_type(8)));
typedef float f32x4 __attribute__((ext_vector_type(4)));
typedef unsigned short u16x4 __attribute__((ext_vector_type(4)));
typedef unsigned short u16x8 __attribute__((ext_vector_type(8)));

static __device__ __forceinline__ unsigned short f2b(float f) {
  __hip_bfloat16 h = __float2bfloat16(f);
  return *reinterpret_cast<unsigned short*>(&h);
}

// K0a: x_cls f32 -> bf16 (row-major [2048][1024])
__global__ __launch_bounds__(256) void k_cvt_x(const float* __restrict__ x,
                                               unsigned short* __restrict__ xb) {
  int i = (blockIdx.x * 256 + threadIdx.x) * 4;
  float4 v = *reinterpret_cast<const float4*>(x + i);
  u16x4 o; o[0] = f2b(v.x); o[1] = f2b(v.y); o[2] = f2b(v.z); o[3] = f2b(v.w);
  *reinterpret_cast<u16x4*>(xb + i) = o;
}

// K0b: WvT[j][k] = bf16(W[k][2048+j]) — transposed V-slice of W_cls
__global__ __launch_bounds__(256) void k_wt(const float* __restrict__ W,
                                            unsigned short* __restrict__ wt) {
  int idx = blockIdx.x * 256 + threadIdx.x;   // 1M threads
  int j = idx >> 10, k = idx & 1023;
  wt[idx] = f2b(W[k * 3072 + 2048 + j]);
}

// K1: v = x @ Wv  (M=2048, N=1024, K=1024), bf16 MFMA 16x16x32, 64x64 tile, 4 waves.
// Writes v into out0[:, 1024+j] (this IS the x_ori output, and serves as v storage).
__global__ __launch_bounds__(256) void k_gemm_v(const unsigned short* __restrict__ xb,
                                                const unsigned short* __restrict__ wt,
                                                float* __restrict__ out0) {
  int j0 = blockIdx.x * 64, n0 = blockIdx.y * 64;
  int t = threadIdx.x, w = t >> 6, l = t & 63, g = l >> 4, c = l & 15;
  const unsigned short* arow = xb + (n0 + w * 16 + c) * CDIM + g * 8;
  f32x4 acc[4] = {};
  for (int kk = 0; kk < CDIM; kk += 32) {
    bf16x8 a = *reinterpret_cast<const bf16x8*>(arow + kk);
#pragma unroll
    for (int cf = 0; cf < 4; ++cf) {
      bf16x8 b = *reinterpret_cast<const bf16x8*>(wt + (j0 + cf * 16 + c) * CDIM + kk + g * 8);
      acc[cf] = __builtin_amdgcn_mfma_f32_16x16x32_bf16(a, b, acc[cf], 0, 0, 0);
    }
  }
#pragma unroll
  for (int cf = 0; cf < 4; ++cf)
#pragma unroll
    for (int r = 0; r < 4; ++r)
      out0[(n0 + w * 16 + g * 4 + r) * (2 * CDIM) + CDIM + j0 + cf * 16 + c] = acc[cf][r];
}

// K2: per (h, n): inv-norm over 128 dims; write vn bf16 [h][n][d] (normalized)
// and vT bf16 [h][d][n] (unnormalized, for PV B-operand).
__global__ __launch_bounds__(256) void k_norm(const float* __restrict__ out0,
                                              unsigned short* __restrict__ vn,
                                              unsigned short* __restrict__ vT) {
  int h = blockIdx.x, n0 = blockIdx.y * 64;
  int t = threadIdx.x;
  int i = t >> 2, dq = (t & 3) * 32;
  __shared__ float red[64][4];
  __shared__ float invn[64];
  __shared__ unsigned short tile[64][136];
  float v[32];
  const float* src = out0 + (n0 + i) * 2048 + 1024 + h * 128 + dq;
  float ss = 0.f;
#pragma unroll
  for (int x = 0; x < 32; x += 4) {
    float4 f = *reinterpret_cast<const float4*>(src + x);
    v[x] = f.x; v[x + 1] = f.y; v[x + 2] = f.z; v[x + 3] = f.w;
    ss += f.x * f.x + f.y * f.y + f.z * f.z + f.w * f.w;
  }
  red[i][t & 3] = ss;
#pragma unroll
  for (int x = 0; x < 32; ++x) tile[i][dq + x] = f2b(v[x]);
  __syncthreads();
  if ((t & 3) == 0) invn[i] = rsqrtf(red[i][0] + red[i][1] + red[i][2] + red[i][3]);
  __syncthreads();
  float inv = invn[i];
  unsigned short* dn = vn + (h * NTOK + n0 + i) * HD + dq;
#pragma unroll
  for (int x = 0; x < 32; x += 8) {
    u16x8 o;
#pragma unroll
    for (int q = 0; q < 8; ++q) o[q] = f2b(v[x + q] * inv);
    *reinterpret_cast<u16x8*>(dn + x) = o;
  }
  int q = t & 3;
#pragma unroll
  for (int pass = 0; pass < 2; ++pass) {
    int dd = (t >> 2) + pass * 64;
    u16x8 a, b;
#pragma unroll
    for (int nn = 0; nn < 8; ++nn) a[nn] = tile[q * 16 + nn][dd];
#pragma unroll
    for (int nn = 0; nn < 8; ++nn) b[nn] = tile[q * 16 + 8 + nn][dd];
    unsigned short* dT = vT + (h * HD + dd) * NTOK + n0 + q * 16;
    *reinterpret_cast<u16x8*>(dT) = a;
    *reinterpret_cast<u16x8*>(dT + 8) = b;
  }
}

// K3: grid (8 h, 64 tiles of 32 rows), 512 threads = 8 waves, wave-private
// m-chunks, no barriers in main loop; partials combined via LDS at the end.
#define XROW 132
#define XSLOT (32 * XROW)
__global__ __launch_bounds__(512, 2) void k_attn_x(const unsigned short* __restrict__ vn,
                                                   const unsigned short* __restrict__ vT,
                                                   float* __restrict__ out0,
                                                   float* __restrict__ denom_ws) {
  int h = blockIdx.x, n0 = blockIdx.y * 32;
  int t = threadIdx.x, w = t >> 6, l = t & 63, g = l >> 4, c = l & 15;
  __shared__ __align__(16) unsigned char smem[68736];
  const unsigned short* vnh = vn + h * NTOK * HD;
  const unsigned short* vTh = vT + h * HD * NTOK;
  bf16x8 afr[2][4];
#pragma unroll
  for (int rf = 0; rf < 2; ++rf)
#pragma unroll
    for (int ks = 0; ks < 4; ++ks)
      afr[rf][ks] = *reinterpret_cast<const bf16x8*>(vnh + (n0 + rf * 16 + c) * HD + ks * 32 + g * 8);
  f32x4 xacc[2][8] = {};
  float rs[8] = {0.f, 0.f, 0.f, 0.f, 0.f, 0.f, 0.f, 0.f};
#pragma unroll 1
  for (int j = 0; j < 4; ++j) {
    int m0 = (j * 8 + w) * 64;
    f32x4 sacc[2][4] = {};
#pragma unroll
    for (int ks = 0; ks < 4; ++ks) {
      bf16x8 bks[4];
#pragma unroll
      for (int cf = 0; cf < 4; ++cf)
        bks[cf] = *reinterpret_cast<const bf16x8*>(vnh + (m0 + cf * 16 + c) * HD + ks * 32 + g * 8);
#pragma unroll
      for (int rf = 0; rf < 2; ++rf)
#pragma unroll
        for (int cf = 0; cf < 4; ++cf)
          sacc[rf][cf] = __builtin_amdgcn_mfma_f32_16x16x32_bf16(afr[rf][ks], bks[cf], sacc[rf][cf], 0, 0, 0);
    }
#pragma unroll
    for (int rf = 0; rf < 2; ++rf)
#pragma unroll
      for (int cf = 0; cf < 4; ++cf)
#pragma unroll
        for (int r = 0; r < 4; ++r) {
          float e = __expf(25.0f * (sacc[rf][cf][r] - 1.0f));
          rs[rf * 4 + r] += e;
          int row = rf * 16 + g * 4 + r;
          int byte = (row * 128 + (cf * 16 + c) * 2) ^ ((row & 7) << 4);
          *reinterpret_cast<unsigned short*>(smem + w * 4096 + byte) = f2b(e);
        }
#pragma unroll
    for (int ks2 = 0; ks2 < 2; ++ks2) {
      bf16x8 bv[8];
#pragma unroll
      for (int dc = 0; dc < 8; ++dc)
        bv[dc] = *reinterpret_cast<const bf16x8*>(vTh + (dc * 16 + c) * NTOK + m0 + ks2 * 32 + g * 8);
#pragma unroll
      for (int rf = 0; rf < 2; ++rf) {
        int prow = rf * 16 + c;
        int pbyte = (prow * 128 + (ks2 * 32 + g * 8) * 2) ^ ((prow & 7) << 4);
        bf16x8 pa = *reinterpret_cast<const bf16x8*>(smem + w * 4096 + pbyte);
#pragma unroll
        for (int dc = 0; dc < 8; ++dc)
          xacc[rf][dc] = __builtin_amdgcn_mfma_f32_16x16x32_bf16(pa, bv[dc], xacc[rf][dc], 0, 0, 0);
      }
    }
  }
#pragma unroll
  for (int i = 0; i < 8; ++i) {
    float v = rs[i];
    v += __shfl_xor(v, 1); v += __shfl_xor(v, 2);
    v += __shfl_xor(v, 4); v += __shfl_xor(v, 8);
    rs[i] = v;
  }
  __syncthreads();
  float* xs = reinterpret_cast<float*>(smem);
  float* dslot = reinterpret_cast<float*>(smem + 67584);
  float* idn = reinterpret_cast<float*>(smem + 68608);
  if (w < 4) {
#pragma unroll
    for (int rf = 0; rf < 2; ++rf)
#pragma unroll
      for (int dc = 0; dc < 8; ++dc)
#pragma unroll
        for (int r = 0; r < 4; ++r)
          xs[w * XSLOT + (rf * 16 + g * 4 + r) * XROW + dc * 16 + c] = xacc[rf][dc][r];
  }
  if (c == 0) {
#pragma unroll
    for (int rf = 0; rf < 2; ++rf)
#pragma unroll
      for (int r = 0; r < 4; ++r)
        dslot[w * 32 + rf * 16 + g * 4 + r] = rs[rf * 4 + r];
  }
  __syncthreads();
  if (w >= 4) {
#pragma unroll
    for (int rf = 0; rf < 2; ++rf)
#pragma unroll
      for (int dc = 0; dc < 8; ++dc)
#pragma unroll
        for (int r = 0; r < 4; ++r)
          xs[(w - 4) * XSLOT + (rf * 16 + g * 4 + r) * XROW + dc * 16 + c] += xacc[rf][dc][r];
  }
  if (t < 32) {
    float d = 0.f;
#pragma unroll
    for (int w8 = 0; w8 < 8; ++w8) d += dslot[w8 * 32 + t];
    denom_ws[h * NTOK + n0 + t] = d;
    idn[t] = 1.0f / d;
  }
  __syncthreads();
  {
    int row = t >> 4, d0 = (t & 15) * 8;
    f32x4 a0 = {}, a1 = {};
#pragma unroll
    for (int s = 0; s < 4; ++s) {
      a0 += *reinterpret_cast<f32x4*>(&xs[s * XSLOT + row * XROW + d0]);
      a1 += *reinterpret_cast<f32x4*>(&xs[s * XSLOT + row * XROW + d0 + 4]);
    }
    float inv = idn[row];
    float* dst = out0 + (size_t)(n0 + row) * 2048 + h * 128 + d0;
    __builtin_nontemporal_store(a0 * inv, reinterpret_cast<f32x4*>(dst));
    __builtin_nontemporal_store(a1 * inv, reinterpret_cast<f32x4*>(dst + 4));
  }
}

// K4 v3: grid (32 m-tiles, 32 n-tiles), 4 waves. The 64x128 B-tile (m-side vn
// rows, shared by all 4 waves) is LDS-staged per head, XOR-swizzled, double-
// buffered (1 barrier/head); next head's staging loads issued before compute.
// out1 written with non-temporal stores (keep vn L2-resident).
__global__ __launch_bounds__(256, 4) void k_sim(const unsigned short* __restrict__ vn,
                                                const float* __restrict__ denom_ws,
                                                float* __restrict__ out1,
                                                float* __restrict__ rowsum) {
  int m0 = blockIdx.x * 64, n0 = blockIdx.y * 64;
  int t = threadIdx.x, w = t >> 6, l = t & 63, g = l >> 4, c = l & 15;
  int nr = n0 + w * 16;
  __shared__ __align__(16) unsigned short Bs[2][64 * 128];
  // staging map: thread t -> row sr, 4 x 16B chunks at col shorts (t&3)*8 + i*32
  int sr = t >> 2, scb = (t & 3) * 16;  // row, col-bytes base
  const unsigned short* gstage = vn + (size_t)(m0 + sr) * HD;
  bf16x8 stg[4];
#pragma unroll
  for (int i = 0; i < 4; ++i)
    stg[i] = *reinterpret_cast<const bf16x8*>(reinterpret_cast<const unsigned char*>(gstage) + scb + i * 64);
  {
    unsigned char* base = reinterpret_cast<unsigned char*>(&Bs[0][0]);
    int rb = sr * 256;
#pragma unroll
    for (int i = 0; i < 4; ++i) {
      int byte = (rb + scb + i * 64) ^ ((sr & 7) << 4);
      *reinterpret_cast<bf16x8*>(base + byte) = stg[i];
    }
  }
  float raw[4][4] = {};
  float sim[4][4] = {};
  __syncthreads();
#pragma unroll 1
  for (int h = 0; h < NH; ++h) {
    const unsigned short* vnh = vn + (size_t)h * NTOK * HD;
    // issue next head's staging loads early (latency hides under compute)
    if (h < NH - 1) {
      const unsigned char* gs = reinterpret_cast<const unsigned char*>(
          vn + ((size_t)(h + 1) * NTOK + m0 + sr) * HD);
#pragma unroll
      for (int i = 0; i < 4; ++i)
        stg[i] = *reinterpret_cast<const bf16x8*>(gs + scb + i * 64);
    }
    // compute from Bs[h&1]
    const unsigned char* bbase = reinterpret_cast<const unsigned char*>(&Bs[h & 1][0]);
    f32x4 sacc[4] = {};
#pragma unroll
    for (int ks = 0; ks < 4; ++ks) {
      bf16x8 a = *reinterpret_cast<const bf16x8*>(vnh + (nr + c) * HD + ks * 32 + g * 8);
#pragma unroll
      for (int cf = 0; cf < 4; ++cf) {
        int row = cf * 16 + c;
        int byte = (row * 256 + ks * 64 + g * 16) ^ ((row & 7) << 4);
        bf16x8 b = *reinterpret_cast<const bf16x8*>(bbase + byte);
        sacc[cf] = __builtin_amdgcn_mfma_f32_16x16x32_bf16(a, b, sacc[cf], 0, 0, 0);
      }
    }
    float id[4];
#pragma unroll
    for (int r = 0; r < 4; ++r) id[r] = 1.0f / denom_ws[h * NTOK + nr + g * 4 + r];
#pragma unroll
    for (int cf = 0; cf < 4; ++cf)
#pragma unroll
      for (int r = 0; r < 4; ++r) {
        float sv = sacc[cf][r];
        raw[cf][r] += sv;
        sim[cf][r] += __expf(25.0f * (sv - 1.0f)) * id[r];
      }
    if (h < NH - 1) {
      unsigned char* base = reinterpret_cast<unsigned char*>(&Bs[(h + 1) & 1][0]);
      int rb = sr * 256;
#pragma unroll
      for (int i = 0; i < 4; ++i) {
        int byte = (rb + scb + i * 64) ^ ((sr & 7) << 4);
        *reinterpret_cast<bf16x8*>(base + byte) = stg[i];
      }
    }
    __syncthreads();
  }
  float rowacc[4] = {0.f, 0.f, 0.f, 0.f};
#pragma unroll
  for (int cf = 0; cf < 4; ++cf)
#pragma unroll
    for (int r = 0; r < 4; ++r) {
      // mask: mean_h raw > 0.75  <=>  sum_h raw > 6.0 ; softmax denoms cancel.
      float val = (raw[cf][r] > 6.0f) ? __expf(sim[cf][r] * 0.125f) : 0.0f;
      __builtin_nontemporal_store(val, &out1[(size_t)(nr + g * 4 + r) * NTOK + m0 + cf * 16 + c]);
      rowacc[r] += val;
    }
#pragma unroll
  for (int r = 0; r < 4; ++r) {
    float v = rowacc[r];
    v += __shfl_xor(v, 1); v += __shfl_xor(v, 2);
    v += __shfl_xor(v, 4); v += __shfl_xor(v, 8);
    rowacc[r] = v;
  }
  if (c == 0) {
#pragma unroll
    for (int r = 0; r < 4; ++r)
      atomicAdd(&rowsum[nr + g * 4 + r], rowacc[r]);
  }
}

// K5: normalize out1 rows by masked-exp row sums.
__global__ __launch_bounds__(256) void k_renorm(float* __restrict__ out1,
                                                const float* __restrict__ rowsum) {
  int row = blockIdx.x;
  float inv = 1.0f / rowsum[row];
  f32x4* p = reinterpret_cast<f32x4*>(out1 + (size_t)row * NTOK);
  for (int c4 = threadIdx.x; c4 < NTOK / 4; c4 += 256) {
    f32x4 v = p[c4];
    __builtin_nontemporal_store(v * inv, &p[c4]);
  }
}

extern "C" void kernel_launch(void* const* d_in, const int* in_sizes, int n_in,
                              void* d_out, int out_size, void* d_ws, size_t ws_size,
                              hipStream_t stream) {
  const float* x_cls = (const float*)d_in[0];
  const float* W_cls = (const float*)d_in[2];
  // d_in[1] (x_reg) and d_in[3] (W_reg) do not feed the outputs.
  float* out0 = (float*)d_out;                       // [2048][2048] concat(x, x_ori)
  float* out1 = (float*)d_out + (size_t)NTOK * 2048; // [2048][2048] sim_round2

  unsigned short* xb = (unsigned short*)d_ws;               // 2M shorts (4MB)
  unsigned short* wt = xb + NTOK * CDIM;                    // 1M shorts (2MB)
  unsigned short* vn = wt + CDIM * CDIM;                    // 2M shorts (4MB)
  unsigned short* vT = vn + NH * NTOK * HD;                 // 2M shorts (4MB)
  float* denom = (float*)(vT + NH * HD * NTOK);             // 16K floats
  float* rowsum = denom + NH * NTOK;                        // 2048 floats

  (void)hipMemsetAsync(rowsum, 0, NTOK * sizeof(float), stream);
  k_cvt_x<<<2048, 256, 0, stream>>>(x_cls, xb);
  k_wt<<<4096, 256, 0, stream>>>(W_cls, wt);
  k_gemm_v<<<dim3(16, 32), 256, 0, stream>>>(xb, wt, out0);
  k_norm<<<dim3(8, 32), 256, 0, stream>>>(out0, vn, vT);
  k_attn_x<<<dim3(8, 64), 512, 0, stream>>>(vn, vT, out0, denom);
  k_sim<<<dim3(32, 32), 256, 0, stream>>>(vn, denom, out1, rowsum);
  k_renorm<<<NTOK, 256, 0, stream>>>(out1, rowsum);
}